// Round 2
// baseline (863.364 us; speedup 1.0000x reference)
//
#include <hip/hip_runtime.h>
#include <stdint.h>

namespace {

constexpr int cNI  = 50000;
constexpr int cNU  = 20000;
constexpr int cNT  = 50000;
constexpr int cNIM = 50000;
constexpr int cEB  = 400000;
constexpr int cETA = 200000;
constexpr int cEIA = 200000;

typedef __bf16 bf16x8 __attribute__((ext_vector_type(8)));
typedef float  floatx4 __attribute__((ext_vector_type(4)));

__device__ __forceinline__ float bf2f(unsigned short u) {
  union { unsigned int i; float f; } c;
  c.i = ((unsigned int)u) << 16;
  return c.f;
}
__device__ __forceinline__ unsigned short f2bf(float f) {
  union { float f; unsigned int i; } c;
  c.f = f;
  unsigned int u = c.i;
  u += 0x7fffu + ((u >> 16) & 1u);  // round-to-nearest-even
  return (unsigned short)(u >> 16);
}
__device__ __forceinline__ float gelu_f(float x) {
  // jax.nn.gelu default: tanh approximation
  float u = 0.7978845608028654f * (x + 0.044715f * x * x * x);
  float e = __expf(2.f * u);
  float t = 1.f - 2.f / (e + 1.f);  // tanh(u), graceful at +-inf
  return 0.5f * x * (1.f + t);
}

// ---------------- combine weights: WkvT[512][256] = [Wka^T ; Wvm^T], p/sqrt(D) folded into Wka
// All source weights are float32; combined weights stored bf16, biases f32.
__global__ __launch_bounds__(256) void combine_kernel(
    const float* __restrict__ Wk_u, const float* __restrict__ bk_u,
    const float* __restrict__ Wv_u, const float* __restrict__ bv_u,
    const float* __restrict__ Wk_t, const float* __restrict__ bk_t,
    const float* __restrict__ Wv_t, const float* __restrict__ bv_t,
    const float* __restrict__ Wk_i, const float* __restrict__ bk_i,
    const float* __restrict__ Wv_i, const float* __restrict__ bv_i,
    const float* __restrict__ a_b, const float* __restrict__ m_b, const float* __restrict__ p_b,
    const float* __restrict__ a_t, const float* __restrict__ m_t, const float* __restrict__ p_t,
    const float* __restrict__ a_i, const float* __restrict__ m_i, const float* __restrict__ p_i,
    const float* __restrict__ Wq, const float* __restrict__ bq,
    const float* __restrict__ Wo, const float* __restrict__ bo,
    unsigned short* __restrict__ WkvT_u, float* __restrict__ bkv_u,
    unsigned short* __restrict__ WkvT_t, float* __restrict__ bkv_t,
    unsigned short* __restrict__ WkvT_i, float* __restrict__ bkv_i,
    unsigned short* __restrict__ WqT, float* __restrict__ bqf,
    unsigned short* __restrict__ WoT, float* __restrict__ bof)
{
  int idx = blockIdx.x * 256 + threadIdx.x;
  if (idx < 3 * 512 * 256) {
    int rel  = idx >> 17;            // 512*256 = 131072
    int rem  = idx & 131071;
    int jrow = rem >> 8;             // 0..511
    int k    = rem & 255;
    int isv  = jrow >> 8;            // 0: attention(kr), 1: message(vr)
    int j = jrow & 255, h = j >> 5, e = j & 31;
    const float *W, *bin, *A, *pp;
    unsigned short* Wout; float* bout;
    if (rel == 0)      { W = isv ? Wv_u : Wk_u; bin = isv ? bv_u : bk_u; A = isv ? m_b : a_b; pp = p_b; Wout = WkvT_u; bout = bkv_u; }
    else if (rel == 1) { W = isv ? Wv_t : Wk_t; bin = isv ? bv_t : bk_t; A = isv ? m_t : a_t; pp = p_t; Wout = WkvT_t; bout = bkv_t; }
    else               { W = isv ? Wv_i : Wk_i; bin = isv ? bv_i : bk_i; A = isv ? m_i : a_i; pp = p_i; Wout = WkvT_i; bout = bkv_i; }
    float scale = isv ? 1.0f : pp[h] * 0.17677669529663687f;  // p[h]/sqrt(32)
    const float* wrow = W + k * 256 + h * 32;
    const float* acol = A + h * 1024 + e;
    float acc = 0.f;
    for (int d = 0; d < 32; ++d) acc += wrow[d] * acol[d * 32];
    Wout[jrow * 256 + k] = f2bf(acc * scale);
    if (k == 0) {
      const float* brow = bin + h * 32;
      float bacc = 0.f;
      for (int d = 0; d < 32; ++d) bacc += brow[d] * acol[d * 32];
      bout[jrow] = bacc * scale;
    }
  } else if (idx < 3 * 512 * 256 + 2 * 256 * 256) {
    int rem = idx - 3 * 512 * 256;
    int which = rem >> 16;
    int r2 = rem & 65535;
    int j = r2 >> 8, k = r2 & 255;
    if (which == 0) { WqT[j * 256 + k] = f2bf(Wq[k * 256 + j]); if (k == 0) bqf[j] = bq[j]; }
    else            { WoT[j * 256 + k] = f2bf(Wo[k * 256 + j]); if (k == 0) bof[j] = bo[j]; }
  }
}

// ---------------- GEMM: C[M,N] = A[M,256] @ BT[N,256]^T + bias, f32 acc
// MODE 0: A is float32 (cast to bf16 during LDS staging), C stored bf16.
// MODE 1: A is bf16 (gagg), C is float32 d_out with skip-blend epilogue (N==256).
template <int MODE>
__global__ __launch_bounds__(256) void gemm_bt_kernel(
    const void* __restrict__ Avp, const unsigned short* __restrict__ BT,
    const float* __restrict__ bias, void* __restrict__ Cvp,
    int M, int N,
    const float* __restrict__ xres, const float* __restrict__ skipp)
{
  __shared__ __align__(16) unsigned short As[64][40];
  __shared__ __align__(16) unsigned short Bs[64][40];
  const int tid = threadIdx.x;
  const int m0 = blockIdx.x * 64;
  const int n0 = blockIdx.y * 64;
  const int wave = tid >> 6, lane = tid & 63;
  const int wm = (wave >> 1) * 32, wn = (wave & 1) * 32;
  const int quad = lane >> 4, l16 = lane & 15;
  floatx4 acc00 = {0.f,0.f,0.f,0.f}, acc01 = {0.f,0.f,0.f,0.f};
  floatx4 acc10 = {0.f,0.f,0.f,0.f}, acc11 = {0.f,0.f,0.f,0.f};
  const int lrow = tid >> 2, lq = tid & 3;
  const int grow = m0 + lrow;
  for (int kt = 0; kt < 256; kt += 32) {
    uint4 av = make_uint4(0u, 0u, 0u, 0u);
    if (MODE == 0) {
      const float* Af = (const float*)Avp;
      if (grow < M) {
        const float4* ap = (const float4*)(Af + (size_t)grow * 256 + kt + lq * 8);
        float4 f0 = ap[0], f1 = ap[1];
        av.x = (unsigned int)f2bf(f0.x) | ((unsigned int)f2bf(f0.y) << 16);
        av.y = (unsigned int)f2bf(f0.z) | ((unsigned int)f2bf(f0.w) << 16);
        av.z = (unsigned int)f2bf(f1.x) | ((unsigned int)f2bf(f1.y) << 16);
        av.w = (unsigned int)f2bf(f1.z) | ((unsigned int)f2bf(f1.w) << 16);
      }
    } else {
      const unsigned short* Ab = (const unsigned short*)Avp;
      if (grow < M) av = *(const uint4*)(Ab + (size_t)grow * 256 + kt + lq * 8);
    }
    uint4 bv = *(const uint4*)(BT + (size_t)(n0 + lrow) * 256 + kt + lq * 8);
    *(uint4*)(&As[lrow][lq * 8]) = av;
    *(uint4*)(&Bs[lrow][lq * 8]) = bv;
    __syncthreads();
    bf16x8 a0 = *(const bf16x8*)(&As[wm + l16][quad * 8]);
    bf16x8 a1 = *(const bf16x8*)(&As[wm + 16 + l16][quad * 8]);
    bf16x8 b0 = *(const bf16x8*)(&Bs[wn + l16][quad * 8]);
    bf16x8 b1 = *(const bf16x8*)(&Bs[wn + 16 + l16][quad * 8]);
    acc00 = __builtin_amdgcn_mfma_f32_16x16x32_bf16(a0, b0, acc00, 0, 0, 0);
    acc01 = __builtin_amdgcn_mfma_f32_16x16x32_bf16(a0, b1, acc01, 0, 0, 0);
    acc10 = __builtin_amdgcn_mfma_f32_16x16x32_bf16(a1, b0, acc10, 0, 0, 0);
    acc11 = __builtin_amdgcn_mfma_f32_16x16x32_bf16(a1, b1, acc11, 0, 0, 0);
    __syncthreads();
  }
  float s = 0.f;
  if (MODE == 1) s = 1.f / (1.f + __expf(-skipp[0]));
  floatx4 accs[2][2] = {{acc00, acc01}, {acc10, acc11}};
  for (int mi = 0; mi < 2; ++mi) {
    for (int ni = 0; ni < 2; ++ni) {
      int col = n0 + wn + ni * 16 + l16;
      int rbase = m0 + wm + mi * 16 + quad * 4;
      float bcol = bias[col];
      for (int r = 0; r < 4; ++r) {
        int row = rbase + r;
        if (row < M) {
          float v = accs[mi][ni][r] + bcol;
          if (MODE == 0) {
            ((unsigned short*)Cvp)[(size_t)row * N + col] = f2bf(v);
          } else {
            float xi = xres[(size_t)row * 256 + col];
            float o = s * v + (1.f - s) * xi;
            ((float*)Cvp)[(size_t)row * 256 + col] = 0.5f * o + 0.5f * xi;
          }
        }
      }
    }
  }
}

// ---------------- CSR build
__global__ __launch_bounds__(256) void hist_kernel(
    const int* __restrict__ ebd, const int* __restrict__ etd, const int* __restrict__ eid,
    int* __restrict__ cnt)
{
  int i = blockIdx.x * 256 + threadIdx.x;
  if (i < cEB)  atomicAdd(&cnt[ebd[i]], 1);
  if (i < cETA) atomicAdd(&cnt[cNI + etd[i]], 1);
  if (i < cEIA) atomicAdd(&cnt[2 * cNI + eid[i]], 1);
}

__global__ __launch_bounds__(1024) void scan_kernel(
    const int* __restrict__ cnt, int* __restrict__ off, int* __restrict__ cur)
{
  __shared__ int wsum[16];
  __shared__ int srun;
  const int tid = threadIdx.x, lane = tid & 63, wid = tid >> 6;
  for (int rel = 0; rel < 3; ++rel) {
    const int* c = cnt + rel * cNI;
    int* o  = off + rel * (cNI + 1);
    int* cu = cur + rel * cNI;
    if (tid == 0) srun = 0;
    __syncthreads();
    for (int base = 0; base < cNI; base += 1024) {
      int i = base + tid;
      int v = (i < cNI) ? c[i] : 0;
      int x = v;
      for (int d = 1; d < 64; d <<= 1) { int t = __shfl_up(x, d, 64); if (lane >= d) x += t; }
      if (lane == 63) wsum[wid] = x;
      __syncthreads();
      if (wid == 0) {
        int sv = (lane < 16) ? wsum[lane] : 0;
        for (int d = 1; d < 16; d <<= 1) { int t = __shfl_up(sv, d, 64); if (lane >= d) sv += t; }
        if (lane < 16) wsum[lane] = sv;
      }
      __syncthreads();
      int woff = (wid == 0) ? 0 : wsum[wid - 1];
      int run = srun;
      int excl = run + woff + x - v;
      if (i < cNI) { o[i] = excl; cu[i] = excl; }
      __syncthreads();
      if (tid == 0) srun = run + wsum[15];
      __syncthreads();
    }
    if (tid == 0) o[cNI] = srun;
    __syncthreads();
  }
}

__global__ __launch_bounds__(256) void scatter_kernel(
    const int* __restrict__ ebs, const int* __restrict__ ebd,
    const int* __restrict__ ets, const int* __restrict__ etd,
    const int* __restrict__ eis, const int* __restrict__ eid,
    int* __restrict__ cur,
    int* __restrict__ ss_b, int* __restrict__ ss_t, int* __restrict__ ss_i)
{
  int i = blockIdx.x * 256 + threadIdx.x;
  if (i < cEB)  { int p = atomicAdd(&cur[ebd[i]], 1);           ss_b[p] = ebs[i]; }
  if (i < cETA) { int p = atomicAdd(&cur[cNI + etd[i]], 1);     ss_t[p] = ets[i]; }
  if (i < cEIA) { int p = atomicAdd(&cur[2 * cNI + eid[i]], 1); ss_i[p] = eis[i]; }
}

// ---------------- per-item attention: one wave per item, lane = head*8 + dgroup (4 dims each)
__global__ __launch_bounds__(256) void attend_kernel(
    const unsigned short* __restrict__ q,
    const unsigned short* __restrict__ kv_u,
    const unsigned short* __restrict__ kv_t,
    const unsigned short* __restrict__ kv_i,
    const int* __restrict__ off,
    const int* __restrict__ ss_b, const int* __restrict__ ss_t, const int* __restrict__ ss_i,
    unsigned short* __restrict__ gout)
{
  const int wave = threadIdx.x >> 6;
  const int lane = threadIdx.x & 63;
  const int item = blockIdx.x * 4 + wave;
  if (item >= cNI) return;
  ushort4 qu = ((const ushort4*)(q + (size_t)item * 256))[lane];
  const float q0 = bf2f(qu.x), q1 = bf2f(qu.y), q2 = bf2f(qu.z), q3 = bf2f(qu.w);
  float t0 = 0.f, t1 = 0.f, t2 = 0.f, t3 = 0.f;

#define DO_REL(KV, OFFBASE, SS, NSRC, EMAX)                                  \
  {                                                                          \
    int e0 = off[(OFFBASE) + item];                                          \
    int e1 = off[(OFFBASE) + item + 1];                                      \
    if (e0 < 0) e0 = 0;                                                      \
    if (e1 > (EMAX)) e1 = (EMAX);                                            \
    float den = 0.f, a0 = 0.f, a1 = 0.f, a2 = 0.f, a3 = 0.f;                 \
    for (int e = e0; e < e1; ++e) {                                          \
      int src = SS[e];                                                       \
      if ((unsigned)src >= (unsigned)(NSRC)) src = 0;                        \
      const ushort4* base = (const ushort4*)((KV) + (size_t)src * 512);      \
      ushort4 ku = base[lane];                                               \
      ushort4 vu = base[64 + lane];                                          \
      float p = bf2f(ku.x) * q0 + bf2f(ku.y) * q1 +                          \
                bf2f(ku.z) * q2 + bf2f(ku.w) * q3;                           \
      p += __shfl_xor(p, 1, 8);                                              \
      p += __shfl_xor(p, 2, 8);                                              \
      p += __shfl_xor(p, 4, 8);                                              \
      p = fminf(fmaxf(p, -30.f), 30.f);                                      \
      float ex = __expf(p);                                                  \
      den += ex;                                                             \
      a0 += ex * bf2f(vu.x); a1 += ex * bf2f(vu.y);                          \
      a2 += ex * bf2f(vu.z); a3 += ex * bf2f(vu.w);                          \
    }                                                                        \
    float inv = 1.f / (den + 1e-16f);                                        \
    t0 += a0 * inv; t1 += a1 * inv; t2 += a2 * inv; t3 += a3 * inv;          \
  }

  DO_REL(kv_u, 0, ss_b, cNU, cEB)
  DO_REL(kv_t, (cNI + 1), ss_t, cNT, cETA)
  DO_REL(kv_i, 2 * (cNI + 1), ss_i, cNIM, cEIA)
#undef DO_REL

  ushort4 o;
  o.x = f2bf(gelu_f(t0));
  o.y = f2bf(gelu_f(t1));
  o.z = f2bf(gelu_f(t2));
  o.w = f2bf(gelu_f(t3));
  ((ushort4*)(gout + (size_t)item * 256))[lane] = o;
}

}  // namespace

extern "C" void kernel_launch(void* const* d_in, const int* in_sizes, int n_in,
                              void* d_out, int out_size, void* d_ws, size_t ws_size,
                              hipStream_t stream) {
  (void)in_sizes; (void)n_in; (void)out_size; (void)ws_size;
  const float* x_user  = (const float*)d_in[0];
  const float* x_item  = (const float*)d_in[1];
  const float* x_taste = (const float*)d_in[2];
  const float* x_image = (const float*)d_in[3];
  const int* eb_src  = (const int*)d_in[4];
  const int* eb_dst  = (const int*)d_in[5];
  const int* eta_src = (const int*)d_in[6];
  const int* eta_dst = (const int*)d_in[7];
  const int* eia_src = (const int*)d_in[8];
  const int* eia_dst = (const int*)d_in[9];
  const float* Wk_u = (const float*)d_in[10];
  const float* bk_u = (const float*)d_in[11];
  const float* Wv_u = (const float*)d_in[12];
  const float* bv_u = (const float*)d_in[13];
  const float* Wk_t = (const float*)d_in[14];
  const float* bk_t = (const float*)d_in[15];
  const float* Wv_t = (const float*)d_in[16];
  const float* bv_t = (const float*)d_in[17];
  const float* Wk_i = (const float*)d_in[18];
  const float* bk_i = (const float*)d_in[19];
  const float* Wv_i = (const float*)d_in[20];
  const float* bv_i = (const float*)d_in[21];
  const float* Wq   = (const float*)d_in[22];
  const float* bq   = (const float*)d_in[23];
  const float* a_b  = (const float*)d_in[24];
  const float* m_b  = (const float*)d_in[25];
  const float* p_b  = (const float*)d_in[26];
  const float* a_t  = (const float*)d_in[27];
  const float* m_t  = (const float*)d_in[28];
  const float* p_t  = (const float*)d_in[29];
  const float* a_i  = (const float*)d_in[30];
  const float* m_i  = (const float*)d_in[31];
  const float* p_i  = (const float*)d_in[32];
  const float* Wo   = (const float*)d_in[33];
  const float* bo   = (const float*)d_in[34];
  const float* skip = (const float*)d_in[35];

  char* p = (char*)d_ws;
  auto alloc = [&](size_t n) -> char* {
    char* r = p;
    p += (n + 255) & ~(size_t)255;
    return r;
  };
  unsigned short* q      = (unsigned short*)alloc((size_t)cNI * 256 * 2);
  unsigned short* kv_u   = (unsigned short*)alloc((size_t)cNU * 512 * 2);
  unsigned short* kv_t   = (unsigned short*)alloc((size_t)cNT * 512 * 2);
  unsigned short* kv_i   = (unsigned short*)alloc((size_t)cNIM * 512 * 2);
  unsigned short* gagg   = (unsigned short*)alloc((size_t)cNI * 256 * 2);
  unsigned short* WkvT_u = (unsigned short*)alloc(512 * 256 * 2);
  unsigned short* WkvT_t = (unsigned short*)alloc(512 * 256 * 2);
  unsigned short* WkvT_i = (unsigned short*)alloc(512 * 256 * 2);
  unsigned short* WqT    = (unsigned short*)alloc(256 * 256 * 2);
  unsigned short* WoT    = (unsigned short*)alloc(256 * 256 * 2);
  float* bkv_u = (float*)alloc(512 * 4);
  float* bkv_t = (float*)alloc(512 * 4);
  float* bkv_i = (float*)alloc(512 * 4);
  float* bqf   = (float*)alloc(256 * 4);
  float* bof   = (float*)alloc(256 * 4);
  int* cnt  = (int*)alloc((size_t)3 * cNI * 4);
  int* off  = (int*)alloc((size_t)3 * (cNI + 1) * 4);
  int* cur  = (int*)alloc((size_t)3 * cNI * 4);
  int* ss_b = (int*)alloc((size_t)cEB * 4);
  int* ss_t = (int*)alloc((size_t)cETA * 4);
  int* ss_i = (int*)alloc((size_t)cEIA * 4);

  hipMemsetAsync(cnt, 0, (size_t)3 * cNI * 4, stream);

  combine_kernel<<<2048, 256, 0, stream>>>(
      Wk_u, bk_u, Wv_u, bv_u, Wk_t, bk_t, Wv_t, bv_t, Wk_i, bk_i, Wv_i, bv_i,
      a_b, m_b, p_b, a_t, m_t, p_t, a_i, m_i, p_i,
      Wq, bq, Wo, bo,
      WkvT_u, bkv_u, WkvT_t, bkv_t, WkvT_i, bkv_i, WqT, bqf, WoT, bof);

  gemm_bt_kernel<0><<<dim3(782, 4), 256, 0, stream>>>(x_item, WqT, bqf, q, cNI, 256, nullptr, nullptr);
  gemm_bt_kernel<0><<<dim3(313, 8), 256, 0, stream>>>(x_user, WkvT_u, bkv_u, kv_u, cNU, 512, nullptr, nullptr);
  gemm_bt_kernel<0><<<dim3(782, 8), 256, 0, stream>>>(x_taste, WkvT_t, bkv_t, kv_t, cNT, 512, nullptr, nullptr);
  gemm_bt_kernel<0><<<dim3(782, 8), 256, 0, stream>>>(x_image, WkvT_i, bkv_i, kv_i, cNIM, 512, nullptr, nullptr);

  hist_kernel<<<1563, 256, 0, stream>>>(eb_dst, eta_dst, eia_dst, cnt);
  scan_kernel<<<1, 1024, 0, stream>>>(cnt, off, cur);
  scatter_kernel<<<1563, 256, 0, stream>>>(eb_src, eb_dst, eta_src, eta_dst, eia_src, eia_dst,
                                           cur, ss_b, ss_t, ss_i);

  attend_kernel<<<12500, 256, 0, stream>>>(q, kv_u, kv_t, kv_i, off, ss_b, ss_t, ss_i, gagg);

  gemm_bt_kernel<1><<<dim3(782, 4), 256, 0, stream>>>(gagg, WoT, bof, d_out,
                                                      cNI, 256, x_item, skip);
}

// Round 3
// 699.596 us; speedup vs baseline: 1.2341x; 1.2341x over previous
//
#include <hip/hip_runtime.h>
#include <stdint.h>

namespace {

constexpr int cNI  = 50000;
constexpr int cNU  = 20000;
constexpr int cNT  = 50000;
constexpr int cNIM = 50000;
constexpr int cEB  = 400000;
constexpr int cETA = 200000;
constexpr int cEIA = 200000;
constexpr int cTOT = 3 * cNI;  // 150000 concatenated dst-count slots

typedef __bf16 bf16x8 __attribute__((ext_vector_type(8)));
typedef float  floatx4 __attribute__((ext_vector_type(4)));

__device__ __forceinline__ float bf2f(unsigned short u) {
  union { unsigned int i; float f; } c;
  c.i = ((unsigned int)u) << 16;
  return c.f;
}
__device__ __forceinline__ unsigned short f2bf(float f) {
  union { float f; unsigned int i; } c;
  c.f = f;
  unsigned int u = c.i;
  u += 0x7fffu + ((u >> 16) & 1u);  // round-to-nearest-even
  return (unsigned short)(u >> 16);
}
__device__ __forceinline__ float gelu_f(float x) {
  // jax.nn.gelu default: tanh approximation
  float u = 0.7978845608028654f * (x + 0.044715f * x * x * x);
  float e = __expf(2.f * u);
  float t = 1.f - 2.f / (e + 1.f);  // tanh(u), graceful at +-inf
  return 0.5f * x * (1.f + t);
}

// ---------------- combine weights: WkvT[512][256] = [Wka^T ; Wvm^T], p/sqrt(D) folded into Wka
// All source weights are float32; combined weights stored bf16, biases f32.
__global__ __launch_bounds__(256) void combine_kernel(
    const float* __restrict__ Wk_u, const float* __restrict__ bk_u,
    const float* __restrict__ Wv_u, const float* __restrict__ bv_u,
    const float* __restrict__ Wk_t, const float* __restrict__ bk_t,
    const float* __restrict__ Wv_t, const float* __restrict__ bv_t,
    const float* __restrict__ Wk_i, const float* __restrict__ bk_i,
    const float* __restrict__ Wv_i, const float* __restrict__ bv_i,
    const float* __restrict__ a_b, const float* __restrict__ m_b, const float* __restrict__ p_b,
    const float* __restrict__ a_t, const float* __restrict__ m_t, const float* __restrict__ p_t,
    const float* __restrict__ a_i, const float* __restrict__ m_i, const float* __restrict__ p_i,
    const float* __restrict__ Wq, const float* __restrict__ bq,
    const float* __restrict__ Wo, const float* __restrict__ bo,
    unsigned short* __restrict__ WkvT_u, float* __restrict__ bkv_u,
    unsigned short* __restrict__ WkvT_t, float* __restrict__ bkv_t,
    unsigned short* __restrict__ WkvT_i, float* __restrict__ bkv_i,
    unsigned short* __restrict__ WqT, float* __restrict__ bqf,
    unsigned short* __restrict__ WoT, float* __restrict__ bof)
{
  int idx = blockIdx.x * 256 + threadIdx.x;
  if (idx < 3 * 512 * 256) {
    int rel  = idx >> 17;            // 512*256 = 131072
    int rem  = idx & 131071;
    int jrow = rem >> 8;             // 0..511
    int k    = rem & 255;
    int isv  = jrow >> 8;            // 0: attention(kr), 1: message(vr)
    int j = jrow & 255, h = j >> 5, e = j & 31;
    const float *W, *bin, *A, *pp;
    unsigned short* Wout; float* bout;
    if (rel == 0)      { W = isv ? Wv_u : Wk_u; bin = isv ? bv_u : bk_u; A = isv ? m_b : a_b; pp = p_b; Wout = WkvT_u; bout = bkv_u; }
    else if (rel == 1) { W = isv ? Wv_t : Wk_t; bin = isv ? bv_t : bk_t; A = isv ? m_t : a_t; pp = p_t; Wout = WkvT_t; bout = bkv_t; }
    else               { W = isv ? Wv_i : Wk_i; bin = isv ? bv_i : bk_i; A = isv ? m_i : a_i; pp = p_i; Wout = WkvT_i; bout = bkv_i; }
    float scale = isv ? 1.0f : pp[h] * 0.17677669529663687f;  // p[h]/sqrt(32)
    const float* wrow = W + k * 256 + h * 32;
    const float* acol = A + h * 1024 + e;
    float acc = 0.f;
    for (int d = 0; d < 32; ++d) acc += wrow[d] * acol[d * 32];
    Wout[jrow * 256 + k] = f2bf(acc * scale);
    if (k == 0) {
      const float* brow = bin + h * 32;
      float bacc = 0.f;
      for (int d = 0; d < 32; ++d) bacc += brow[d] * acol[d * 32];
      bout[jrow] = bacc * scale;
    }
  } else if (idx < 3 * 512 * 256 + 2 * 256 * 256) {
    int rem = idx - 3 * 512 * 256;
    int which = rem >> 16;
    int r2 = rem & 65535;
    int j = r2 >> 8, k = r2 & 255;
    if (which == 0) { WqT[j * 256 + k] = f2bf(Wq[k * 256 + j]); if (k == 0) bqf[j] = bq[j]; }
    else            { WoT[j * 256 + k] = f2bf(Wo[k * 256 + j]); if (k == 0) bof[j] = bo[j]; }
  }
}

// ---------------- GEMM: C[M,N] = A[M,256] @ BT[N,256]^T + bias, f32 acc
// MODE 0: A is float32 (cast to bf16 during LDS staging), C stored bf16.
// MODE 1: A is bf16 (gagg), C is float32 d_out with skip-blend epilogue (N==256).
template <int MODE>
__global__ __launch_bounds__(256) void gemm_bt_kernel(
    const void* __restrict__ Avp, const unsigned short* __restrict__ BT,
    const float* __restrict__ bias, void* __restrict__ Cvp,
    int M, int N,
    const float* __restrict__ xres, const float* __restrict__ skipp)
{
  __shared__ __align__(16) unsigned short As[64][40];
  __shared__ __align__(16) unsigned short Bs[64][40];
  const int tid = threadIdx.x;
  const int m0 = blockIdx.x * 64;
  const int n0 = blockIdx.y * 64;
  const int wave = tid >> 6, lane = tid & 63;
  const int wm = (wave >> 1) * 32, wn = (wave & 1) * 32;
  const int quad = lane >> 4, l16 = lane & 15;
  floatx4 acc00 = {0.f,0.f,0.f,0.f}, acc01 = {0.f,0.f,0.f,0.f};
  floatx4 acc10 = {0.f,0.f,0.f,0.f}, acc11 = {0.f,0.f,0.f,0.f};
  const int lrow = tid >> 2, lq = tid & 3;
  const int grow = m0 + lrow;
  for (int kt = 0; kt < 256; kt += 32) {
    uint4 av = make_uint4(0u, 0u, 0u, 0u);
    if (MODE == 0) {
      const float* Af = (const float*)Avp;
      if (grow < M) {
        const float4* ap = (const float4*)(Af + (size_t)grow * 256 + kt + lq * 8);
        float4 f0 = ap[0], f1 = ap[1];
        av.x = (unsigned int)f2bf(f0.x) | ((unsigned int)f2bf(f0.y) << 16);
        av.y = (unsigned int)f2bf(f0.z) | ((unsigned int)f2bf(f0.w) << 16);
        av.z = (unsigned int)f2bf(f1.x) | ((unsigned int)f2bf(f1.y) << 16);
        av.w = (unsigned int)f2bf(f1.z) | ((unsigned int)f2bf(f1.w) << 16);
      }
    } else {
      const unsigned short* Ab = (const unsigned short*)Avp;
      if (grow < M) av = *(const uint4*)(Ab + (size_t)grow * 256 + kt + lq * 8);
    }
    uint4 bv = *(const uint4*)(BT + (size_t)(n0 + lrow) * 256 + kt + lq * 8);
    *(uint4*)(&As[lrow][lq * 8]) = av;
    *(uint4*)(&Bs[lrow][lq * 8]) = bv;
    __syncthreads();
    bf16x8 a0 = *(const bf16x8*)(&As[wm + l16][quad * 8]);
    bf16x8 a1 = *(const bf16x8*)(&As[wm + 16 + l16][quad * 8]);
    bf16x8 b0 = *(const bf16x8*)(&Bs[wn + l16][quad * 8]);
    bf16x8 b1 = *(const bf16x8*)(&Bs[wn + 16 + l16][quad * 8]);
    acc00 = __builtin_amdgcn_mfma_f32_16x16x32_bf16(a0, b0, acc00, 0, 0, 0);
    acc01 = __builtin_amdgcn_mfma_f32_16x16x32_bf16(a0, b1, acc01, 0, 0, 0);
    acc10 = __builtin_amdgcn_mfma_f32_16x16x32_bf16(a1, b0, acc10, 0, 0, 0);
    acc11 = __builtin_amdgcn_mfma_f32_16x16x32_bf16(a1, b1, acc11, 0, 0, 0);
    __syncthreads();
  }
  float s = 0.f;
  if (MODE == 1) s = 1.f / (1.f + __expf(-skipp[0]));
  floatx4 accs[2][2] = {{acc00, acc01}, {acc10, acc11}};
  for (int mi = 0; mi < 2; ++mi) {
    for (int ni = 0; ni < 2; ++ni) {
      int col = n0 + wn + ni * 16 + l16;
      int rbase = m0 + wm + mi * 16 + quad * 4;
      float bcol = bias[col];
      for (int r = 0; r < 4; ++r) {
        int row = rbase + r;
        if (row < M) {
          float v = accs[mi][ni][r] + bcol;
          if (MODE == 0) {
            ((unsigned short*)Cvp)[(size_t)row * N + col] = f2bf(v);
          } else {
            float xi = xres[(size_t)row * 256 + col];
            float o = s * v + (1.f - s) * xi;
            ((float*)Cvp)[(size_t)row * 256 + col] = 0.5f * o + 0.5f * xi;
          }
        }
      }
    }
  }
}

// ---------------- CSR build
__global__ __launch_bounds__(256) void hist_kernel(
    const int* __restrict__ ebd, const int* __restrict__ etd, const int* __restrict__ eid,
    int* __restrict__ cnt)
{
  int i = blockIdx.x * 256 + threadIdx.x;
  if (i < cEB)  atomicAdd(&cnt[ebd[i]], 1);
  if (i < cETA) atomicAdd(&cnt[cNI + etd[i]], 1);
  if (i < cEIA) atomicAdd(&cnt[2 * cNI + eid[i]], 1);
}

// 3-phase parallel scan over the concatenated 150000 counts.
// Per-relation offsets = global prefix minus known relation bases (EB, EB+ETA),
// since each relation's counts sum to exactly its edge count.
__global__ __launch_bounds__(256) void scan1_kernel(
    const int* __restrict__ cnt, int* __restrict__ tpre, int* __restrict__ bsum)
{
  __shared__ int wsum[4];
  const int tid = threadIdx.x, lane = tid & 63, wid = tid >> 6;
  const int base = blockIdx.x * 4096 + tid * 16;
  int s = 0;
  if (base + 16 <= cTOT) {
    const int4* p4 = (const int4*)(cnt + base);
    for (int j = 0; j < 4; ++j) { int4 v = p4[j]; s += v.x + v.y + v.z + v.w; }
  } else {
    for (int j = 0; j < 16; ++j) { int i = base + j; if (i < cTOT) s += cnt[i]; }
  }
  int x = s;
  for (int d = 1; d < 64; d <<= 1) { int t = __shfl_up(x, d, 64); if (lane >= d) x += t; }
  if (lane == 63) wsum[wid] = x;
  __syncthreads();
  int wb = 0;
  for (int w = 0; w < 4; ++w) { int v = wsum[w]; if (w < wid) wb += v; }
  tpre[blockIdx.x * 256 + tid] = wb + x - s;  // exclusive-within-block thread base
  if (tid == 255) bsum[blockIdx.x] = wb + x;  // block total
}

__global__ __launch_bounds__(64) void scan2_kernel(
    const int* __restrict__ bsum, int* __restrict__ bbase, int* __restrict__ off,
    int nblocks)
{
  const int lane = threadIdx.x;
  int v = (lane < nblocks) ? bsum[lane] : 0;
  int x = v;
  for (int d = 1; d < 64; d <<= 1) { int t = __shfl_up(x, d, 64); if (lane >= d) x += t; }
  if (lane < nblocks) bbase[lane] = x - v;
  if (lane == 0) {
    off[cNI] = cEB;
    off[(cNI + 1) + cNI] = cETA;
    off[2 * (cNI + 1) + cNI] = cEIA;
  }
}

__global__ __launch_bounds__(256) void scan3_kernel(
    const int* __restrict__ cnt, const int* __restrict__ tpre,
    const int* __restrict__ bbase, int* __restrict__ off, int* __restrict__ cur)
{
  const int tid = threadIdx.x;
  const int b = blockIdx.x;
  const int base = b * 4096 + tid * 16;
  int run = bbase[b] + tpre[b * 256 + tid];
  for (int j = 0; j < 16; ++j) {
    int i = base + j;
    if (i >= cTOT) break;
    int rel = (i >= 2 * cNI) ? 2 : (i >= cNI ? 1 : 0);
    int pos = i - rel * cNI;
    int relbase = (rel == 0) ? 0 : (rel == 1) ? cEB : (cEB + cETA);
    int val = run - relbase;
    off[rel * (cNI + 1) + pos] = val;
    cur[rel * cNI + pos] = val;
    run += cnt[i];
  }
}

__global__ __launch_bounds__(256) void scatter_kernel(
    const int* __restrict__ ebs, const int* __restrict__ ebd,
    const int* __restrict__ ets, const int* __restrict__ etd,
    const int* __restrict__ eis, const int* __restrict__ eid,
    int* __restrict__ cur,
    int* __restrict__ ss_b, int* __restrict__ ss_t, int* __restrict__ ss_i)
{
  int i = blockIdx.x * 256 + threadIdx.x;
  if (i < cEB)  { int p = atomicAdd(&cur[ebd[i]], 1);           ss_b[p] = ebs[i]; }
  if (i < cETA) { int p = atomicAdd(&cur[cNI + etd[i]], 1);     ss_t[p] = ets[i]; }
  if (i < cEIA) { int p = atomicAdd(&cur[2 * cNI + eid[i]], 1); ss_i[p] = eis[i]; }
}

// ---------------- per-item attention: one wave per item, lane = head*8 + dgroup (4 dims each)
// 2-edge unroll: issue both edges' gathers before computing either (2x MLP on the
// dependent SS[e] -> kv[src] chain).
__global__ __launch_bounds__(256) void attend_kernel(
    const unsigned short* __restrict__ q,
    const unsigned short* __restrict__ kv_u,
    const unsigned short* __restrict__ kv_t,
    const unsigned short* __restrict__ kv_i,
    const int* __restrict__ off,
    const int* __restrict__ ss_b, const int* __restrict__ ss_t, const int* __restrict__ ss_i,
    unsigned short* __restrict__ gout)
{
  const int wave = threadIdx.x >> 6;
  const int lane = threadIdx.x & 63;
  const int item = blockIdx.x * 4 + wave;
  if (item >= cNI) return;
  ushort4 qu = ((const ushort4*)(q + (size_t)item * 256))[lane];
  const float q0 = bf2f(qu.x), q1 = bf2f(qu.y), q2 = bf2f(qu.z), q3 = bf2f(qu.w);
  float t0 = 0.f, t1 = 0.f, t2 = 0.f, t3 = 0.f;

#define EDGE_DOT(ku, vu, den, a0, a1, a2, a3)                                \
  {                                                                          \
    float p = bf2f(ku.x) * q0 + bf2f(ku.y) * q1 +                            \
              bf2f(ku.z) * q2 + bf2f(ku.w) * q3;                             \
    p += __shfl_xor(p, 1, 8);                                                \
    p += __shfl_xor(p, 2, 8);                                                \
    p += __shfl_xor(p, 4, 8);                                                \
    p = fminf(fmaxf(p, -30.f), 30.f);                                        \
    float ex = __expf(p);                                                    \
    den += ex;                                                               \
    a0 += ex * bf2f(vu.x); a1 += ex * bf2f(vu.y);                            \
    a2 += ex * bf2f(vu.z); a3 += ex * bf2f(vu.w);                            \
  }

#define DO_REL(KV, OFFBASE, SS, NSRC)                                        \
  {                                                                          \
    int e0 = off[(OFFBASE) + item];                                          \
    int e1 = off[(OFFBASE) + item + 1];                                      \
    float den = 0.f, a0 = 0.f, a1 = 0.f, a2 = 0.f, a3 = 0.f;                 \
    int e = e0;                                                              \
    for (; e + 2 <= e1; e += 2) {                                            \
      int s0 = SS[e], s1 = SS[e + 1];                                        \
      if ((unsigned)s0 >= (unsigned)(NSRC)) s0 = 0;                          \
      if ((unsigned)s1 >= (unsigned)(NSRC)) s1 = 0;                          \
      const ushort4* b0p = (const ushort4*)((KV) + (size_t)s0 * 512);        \
      const ushort4* b1p = (const ushort4*)((KV) + (size_t)s1 * 512);        \
      ushort4 k0 = b0p[lane];                                                \
      ushort4 v0 = b0p[64 + lane];                                           \
      ushort4 k1 = b1p[lane];                                                \
      ushort4 v1 = b1p[64 + lane];                                           \
      EDGE_DOT(k0, v0, den, a0, a1, a2, a3)                                  \
      EDGE_DOT(k1, v1, den, a0, a1, a2, a3)                                  \
    }                                                                        \
    if (e < e1) {                                                            \
      int s0 = SS[e];                                                        \
      if ((unsigned)s0 >= (unsigned)(NSRC)) s0 = 0;                          \
      const ushort4* b0p = (const ushort4*)((KV) + (size_t)s0 * 512);        \
      ushort4 k0 = b0p[lane];                                                \
      ushort4 v0 = b0p[64 + lane];                                           \
      EDGE_DOT(k0, v0, den, a0, a1, a2, a3)                                  \
    }                                                                        \
    float inv = 1.f / (den + 1e-16f);                                        \
    t0 += a0 * inv; t1 += a1 * inv; t2 += a2 * inv; t3 += a3 * inv;          \
  }

  DO_REL(kv_u, 0, ss_b, cNU)
  DO_REL(kv_t, (cNI + 1), ss_t, cNT)
  DO_REL(kv_i, 2 * (cNI + 1), ss_i, cNIM)
#undef DO_REL
#undef EDGE_DOT

  ushort4 o;
  o.x = f2bf(gelu_f(t0));
  o.y = f2bf(gelu_f(t1));
  o.z = f2bf(gelu_f(t2));
  o.w = f2bf(gelu_f(t3));
  ((ushort4*)(gout + (size_t)item * 256))[lane] = o;
}

}  // namespace

extern "C" void kernel_launch(void* const* d_in, const int* in_sizes, int n_in,
                              void* d_out, int out_size, void* d_ws, size_t ws_size,
                              hipStream_t stream) {
  (void)in_sizes; (void)n_in; (void)out_size; (void)ws_size;
  const float* x_user  = (const float*)d_in[0];
  const float* x_item  = (const float*)d_in[1];
  const float* x_taste = (const float*)d_in[2];
  const float* x_image = (const float*)d_in[3];
  const int* eb_src  = (const int*)d_in[4];
  const int* eb_dst  = (const int*)d_in[5];
  const int* eta_src = (const int*)d_in[6];
  const int* eta_dst = (const int*)d_in[7];
  const int* eia_src = (const int*)d_in[8];
  const int* eia_dst = (const int*)d_in[9];
  const float* Wk_u = (const float*)d_in[10];
  const float* bk_u = (const float*)d_in[11];
  const float* Wv_u = (const float*)d_in[12];
  const float* bv_u = (const float*)d_in[13];
  const float* Wk_t = (const float*)d_in[14];
  const float* bk_t = (const float*)d_in[15];
  const float* Wv_t = (const float*)d_in[16];
  const float* bv_t = (const float*)d_in[17];
  const float* Wk_i = (const float*)d_in[18];
  const float* bk_i = (const float*)d_in[19];
  const float* Wv_i = (const float*)d_in[20];
  const float* bv_i = (const float*)d_in[21];
  const float* Wq   = (const float*)d_in[22];
  const float* bq   = (const float*)d_in[23];
  const float* a_b  = (const float*)d_in[24];
  const float* m_b  = (const float*)d_in[25];
  const float* p_b  = (const float*)d_in[26];
  const float* a_t  = (const float*)d_in[27];
  const float* m_t  = (const float*)d_in[28];
  const float* p_t  = (const float*)d_in[29];
  const float* a_i  = (const float*)d_in[30];
  const float* m_i  = (const float*)d_in[31];
  const float* p_i  = (const float*)d_in[32];
  const float* Wo   = (const float*)d_in[33];
  const float* bo   = (const float*)d_in[34];
  const float* skip = (const float*)d_in[35];

  char* p = (char*)d_ws;
  auto alloc = [&](size_t n) -> char* {
    char* r = p;
    p += (n + 255) & ~(size_t)255;
    return r;
  };
  unsigned short* q      = (unsigned short*)alloc((size_t)cNI * 256 * 2);
  unsigned short* kv_u   = (unsigned short*)alloc((size_t)cNU * 512 * 2);
  unsigned short* kv_t   = (unsigned short*)alloc((size_t)cNT * 512 * 2);
  unsigned short* kv_i   = (unsigned short*)alloc((size_t)cNIM * 512 * 2);
  unsigned short* gagg   = (unsigned short*)alloc((size_t)cNI * 256 * 2);
  unsigned short* WkvT_u = (unsigned short*)alloc(512 * 256 * 2);
  unsigned short* WkvT_t = (unsigned short*)alloc(512 * 256 * 2);
  unsigned short* WkvT_i = (unsigned short*)alloc(512 * 256 * 2);
  unsigned short* WqT    = (unsigned short*)alloc(256 * 256 * 2);
  unsigned short* WoT    = (unsigned short*)alloc(256 * 256 * 2);
  float* bkv_u = (float*)alloc(512 * 4);
  float* bkv_t = (float*)alloc(512 * 4);
  float* bkv_i = (float*)alloc(512 * 4);
  float* bqf   = (float*)alloc(256 * 4);
  float* bof   = (float*)alloc(256 * 4);
  int* cnt   = (int*)alloc((size_t)cTOT * 4);
  int* off   = (int*)alloc((size_t)3 * (cNI + 1) * 4);
  int* cur   = (int*)alloc((size_t)cTOT * 4);
  int* tpre  = (int*)alloc((size_t)37 * 256 * 4);
  int* bsum  = (int*)alloc(64 * 4);
  int* bbase = (int*)alloc(64 * 4);
  int* ss_b = (int*)alloc((size_t)cEB * 4);
  int* ss_t = (int*)alloc((size_t)cETA * 4);
  int* ss_i = (int*)alloc((size_t)cEIA * 4);

  hipMemsetAsync(cnt, 0, (size_t)cTOT * 4, stream);

  combine_kernel<<<2048, 256, 0, stream>>>(
      Wk_u, bk_u, Wv_u, bv_u, Wk_t, bk_t, Wv_t, bv_t, Wk_i, bk_i, Wv_i, bv_i,
      a_b, m_b, p_b, a_t, m_t, p_t, a_i, m_i, p_i,
      Wq, bq, Wo, bo,
      WkvT_u, bkv_u, WkvT_t, bkv_t, WkvT_i, bkv_i, WqT, bqf, WoT, bof);

  gemm_bt_kernel<0><<<dim3(782, 4), 256, 0, stream>>>(x_item, WqT, bqf, q, cNI, 256, nullptr, nullptr);
  gemm_bt_kernel<0><<<dim3(313, 8), 256, 0, stream>>>(x_user, WkvT_u, bkv_u, kv_u, cNU, 512, nullptr, nullptr);
  gemm_bt_kernel<0><<<dim3(782, 8), 256, 0, stream>>>(x_taste, WkvT_t, bkv_t, kv_t, cNT, 512, nullptr, nullptr);
  gemm_bt_kernel<0><<<dim3(782, 8), 256, 0, stream>>>(x_image, WkvT_i, bkv_i, kv_i, cNIM, 512, nullptr, nullptr);

  hist_kernel<<<1563, 256, 0, stream>>>(eb_dst, eta_dst, eia_dst, cnt);
  scan1_kernel<<<37, 256, 0, stream>>>(cnt, tpre, bsum);
  scan2_kernel<<<1, 64, 0, stream>>>(bsum, bbase, off, 37);
  scan3_kernel<<<37, 256, 0, stream>>>(cnt, tpre, bbase, off, cur);
  scatter_kernel<<<1563, 256, 0, stream>>>(eb_src, eb_dst, eta_src, eta_dst, eia_src, eia_dst,
                                           cur, ss_b, ss_t, ss_i);

  attend_kernel<<<12500, 256, 0, stream>>>(q, kv_u, kv_t, kv_i, off, ss_b, ss_t, ss_i, gagg);

  gemm_bt_kernel<1><<<dim3(782, 4), 256, 0, stream>>>(gagg, WoT, bof, d_out,
                                                      cNI, 256, x_item, skip);
}

// Round 4
// 642.373 us; speedup vs baseline: 1.3440x; 1.0891x over previous
//
#include <hip/hip_runtime.h>
#include <stdint.h>

namespace {

constexpr int cNI  = 50000;
constexpr int cNU  = 20000;
constexpr int cNT  = 50000;
constexpr int cNIM = 50000;
constexpr int cEB  = 400000;
constexpr int cETA = 200000;
constexpr int cEIA = 200000;
constexpr int cTOT = 3 * cNI;  // 150000 concatenated dst-count slots
constexpr int cSCANB = 37;     // ceil(150000/4096)

// strip counts (64 rows per strip)
constexpr int cSQ  = (cNI  + 63) / 64;   // 782
constexpr int cSU  = (cNU  + 63) / 64;   // 313
constexpr int cST  = (cNT  + 63) / 64;   // 782
constexpr int cSIM = (cNIM + 63) / 64;   // 782

typedef __bf16 bf16x8 __attribute__((ext_vector_type(8)));
typedef float  floatx4 __attribute__((ext_vector_type(4)));

__device__ __forceinline__ float bf2f(unsigned short u) {
  union { unsigned int i; float f; } c;
  c.i = ((unsigned int)u) << 16;
  return c.f;
}
__device__ __forceinline__ unsigned short f2bf(float f) {
  union { float f; unsigned int i; } c;
  c.f = f;
  unsigned int u = c.i;
  u += 0x7fffu + ((u >> 16) & 1u);  // round-to-nearest-even
  return (unsigned short)(u >> 16);
}
__device__ __forceinline__ float gelu_f(float x) {
  float u = 0.7978845608028654f * (x + 0.044715f * x * x * x);
  float e = __expf(2.f * u);
  float t = 1.f - 2.f / (e + 1.f);
  return 0.5f * x * (1.f + t);
}

// ---------------- combine weights: WkvT[512][256] = [Wka^T ; Wvm^T], p/sqrt(D) folded into Wka
__global__ __launch_bounds__(256) void combine_kernel(
    const float* __restrict__ Wk_u, const float* __restrict__ bk_u,
    const float* __restrict__ Wv_u, const float* __restrict__ bv_u,
    const float* __restrict__ Wk_t, const float* __restrict__ bk_t,
    const float* __restrict__ Wv_t, const float* __restrict__ bv_t,
    const float* __restrict__ Wk_i, const float* __restrict__ bk_i,
    const float* __restrict__ Wv_i, const float* __restrict__ bv_i,
    const float* __restrict__ a_b, const float* __restrict__ m_b, const float* __restrict__ p_b,
    const float* __restrict__ a_t, const float* __restrict__ m_t, const float* __restrict__ p_t,
    const float* __restrict__ a_i, const float* __restrict__ m_i, const float* __restrict__ p_i,
    const float* __restrict__ Wq, const float* __restrict__ bq,
    const float* __restrict__ Wo, const float* __restrict__ bo,
    unsigned short* __restrict__ WkvT_u, float* __restrict__ bkv_u,
    unsigned short* __restrict__ WkvT_t, float* __restrict__ bkv_t,
    unsigned short* __restrict__ WkvT_i, float* __restrict__ bkv_i,
    unsigned short* __restrict__ WqT, float* __restrict__ bqf,
    unsigned short* __restrict__ WoT, float* __restrict__ bof)
{
  int idx = blockIdx.x * 256 + threadIdx.x;
  if (idx < 3 * 512 * 256) {
    int rel  = idx >> 17;
    int rem  = idx & 131071;
    int jrow = rem >> 8;
    int k    = rem & 255;
    int isv  = jrow >> 8;
    int j = jrow & 255, h = j >> 5, e = j & 31;
    const float *W, *bin, *A, *pp;
    unsigned short* Wout; float* bout;
    if (rel == 0)      { W = isv ? Wv_u : Wk_u; bin = isv ? bv_u : bk_u; A = isv ? m_b : a_b; pp = p_b; Wout = WkvT_u; bout = bkv_u; }
    else if (rel == 1) { W = isv ? Wv_t : Wk_t; bin = isv ? bv_t : bk_t; A = isv ? m_t : a_t; pp = p_t; Wout = WkvT_t; bout = bkv_t; }
    else               { W = isv ? Wv_i : Wk_i; bin = isv ? bv_i : bk_i; A = isv ? m_i : a_i; pp = p_i; Wout = WkvT_i; bout = bkv_i; }
    float scale = isv ? 1.0f : pp[h] * 0.17677669529663687f;  // p[h]/sqrt(32)
    const float* wrow = W + k * 256 + h * 32;
    const float* acol = A + h * 1024 + e;
    float acc = 0.f;
    for (int d = 0; d < 32; ++d) acc += wrow[d] * acol[d * 32];
    Wout[jrow * 256 + k] = f2bf(acc * scale);
    if (k == 0) {
      const float* brow = bin + h * 32;
      float bacc = 0.f;
      for (int d = 0; d < 32; ++d) bacc += brow[d] * acol[d * 32];
      bout[jrow] = bacc * scale;
    }
  } else if (idx < 3 * 512 * 256 + 2 * 256 * 256) {
    int rem = idx - 3 * 512 * 256;
    int which = rem >> 16;
    int r2 = rem & 65535;
    int j = r2 >> 8, k = r2 & 255;
    if (which == 0) { WqT[j * 256 + k] = f2bf(Wq[k * 256 + j]); if (k == 0) bqf[j] = bq[j]; }
    else            { WoT[j * 256 + k] = f2bf(Wo[k * 256 + j]); if (k == 0) bof[j] = bo[j]; }
  }
}

// ---------------- strip GEMM: block owns 64 rows x full N. A staged to LDS ONCE
// (8 k-chunk buffers in the proven 64x40 layout), a-frags hoisted to VGPRs, then
// sweep 64-col n-tiles restaging only B (tiny, L2-hot).
// MODE 0: A f32 (inline cast), C bf16, 4-segment fused projection dispatch.
// MODE 1: A bf16, C f32 with skip/residual epilogue (N==256, single segment).
template <int MODE>
__global__ __launch_bounds__(256) void gemm_strip_kernel(
    const void* __restrict__ A0, const unsigned short* __restrict__ B0,
    const float* __restrict__ bias0, void* __restrict__ C0, int M0, int N0,
    const void* __restrict__ A1, const unsigned short* __restrict__ B1,
    const float* __restrict__ bias1, void* __restrict__ C1, int M1, int N1,
    const void* __restrict__ A2, const unsigned short* __restrict__ B2,
    const float* __restrict__ bias2, void* __restrict__ C2, int M2, int N2,
    const void* __restrict__ A3, const unsigned short* __restrict__ B3,
    const float* __restrict__ bias3, void* __restrict__ C3, int M3, int N3,
    const float* __restrict__ xres, const float* __restrict__ skipp)
{
  __shared__ __align__(16) unsigned short As[8][64][40];
  __shared__ __align__(16) unsigned short Bs[8][64][40];

  const void* Avp; const unsigned short* BT; const float* bias; void* Cvp;
  int M, N, strip;
  int b = blockIdx.x;
  if (MODE == 1 || b < cSQ)            { Avp = A0; BT = B0; bias = bias0; Cvp = C0; M = M0; N = N0; strip = b; }
  else if (b < cSQ + cSU)              { Avp = A1; BT = B1; bias = bias1; Cvp = C1; M = M1; N = N1; strip = b - cSQ; }
  else if (b < cSQ + cSU + cST)        { Avp = A2; BT = B2; bias = bias2; Cvp = C2; M = M2; N = N2; strip = b - cSQ - cSU; }
  else                                 { Avp = A3; BT = B3; bias = bias3; Cvp = C3; M = M3; N = N3; strip = b - cSQ - cSU - cST; }

  const int tid = threadIdx.x;
  const int m0 = strip * 64;
  const int wave = tid >> 6, lane = tid & 63;
  const int wm = (wave >> 1) * 32, wn = (wave & 1) * 32;
  const int quad = lane >> 4, l16 = lane & 15;
  const int lrow = tid >> 2, lq = tid & 3;
  const int grow = m0 + lrow;

  // ---- stage full A strip (64 x 256) once
#pragma unroll
  for (int kt = 0; kt < 8; ++kt) {
    uint4 av = make_uint4(0u, 0u, 0u, 0u);
    if (MODE == 0) {
      if (grow < M) {
        const float4* ap = (const float4*)((const float*)Avp + (size_t)grow * 256 + kt * 32 + lq * 8);
        float4 f0 = ap[0], f1 = ap[1];
        av.x = (unsigned int)f2bf(f0.x) | ((unsigned int)f2bf(f0.y) << 16);
        av.y = (unsigned int)f2bf(f0.z) | ((unsigned int)f2bf(f0.w) << 16);
        av.z = (unsigned int)f2bf(f1.x) | ((unsigned int)f2bf(f1.y) << 16);
        av.w = (unsigned int)f2bf(f1.z) | ((unsigned int)f2bf(f1.w) << 16);
      }
    } else {
      if (grow < M) av = *(const uint4*)((const unsigned short*)Avp + (size_t)grow * 256 + kt * 32 + lq * 8);
    }
    *(uint4*)(&As[kt][lrow][lq * 8]) = av;
  }
  __syncthreads();

  // ---- hoist this wave's a-fragments into registers (A LDS read once per block)
  bf16x8 af0[8], af1[8];
#pragma unroll
  for (int kt = 0; kt < 8; ++kt) {
    af0[kt] = *(const bf16x8*)(&As[kt][wm + l16][quad * 8]);
    af1[kt] = *(const bf16x8*)(&As[kt][wm + 16 + l16][quad * 8]);
  }

  float s = 0.f;
  if (MODE == 1) s = 1.f / (1.f + __expf(-skipp[0]));

  const int ntiles = N >> 6;
  for (int nt = 0; nt < ntiles; ++nt) {
    const int n0 = nt * 64;
    // stage B tile (64 x 256 k) — tiny matrix, L2-hot
#pragma unroll
    for (int kt = 0; kt < 8; ++kt) {
      uint4 bv = *(const uint4*)(BT + (size_t)(n0 + lrow) * 256 + kt * 32 + lq * 8);
      *(uint4*)(&Bs[kt][lrow][lq * 8]) = bv;
    }
    __syncthreads();

    floatx4 acc00 = {0.f,0.f,0.f,0.f}, acc01 = {0.f,0.f,0.f,0.f};
    floatx4 acc10 = {0.f,0.f,0.f,0.f}, acc11 = {0.f,0.f,0.f,0.f};
#pragma unroll
    for (int kt = 0; kt < 8; ++kt) {
      bf16x8 b0 = *(const bf16x8*)(&Bs[kt][wn + l16][quad * 8]);
      bf16x8 b1 = *(const bf16x8*)(&Bs[kt][wn + 16 + l16][quad * 8]);
      acc00 = __builtin_amdgcn_mfma_f32_16x16x32_bf16(af0[kt], b0, acc00, 0, 0, 0);
      acc01 = __builtin_amdgcn_mfma_f32_16x16x32_bf16(af0[kt], b1, acc01, 0, 0, 0);
      acc10 = __builtin_amdgcn_mfma_f32_16x16x32_bf16(af1[kt], b0, acc10, 0, 0, 0);
      acc11 = __builtin_amdgcn_mfma_f32_16x16x32_bf16(af1[kt], b1, acc11, 0, 0, 0);
    }

    // epilogue for this n-tile
    floatx4 accs[2][2] = {{acc00, acc01}, {acc10, acc11}};
#pragma unroll
    for (int mi = 0; mi < 2; ++mi) {
#pragma unroll
      for (int ni = 0; ni < 2; ++ni) {
        int col = n0 + wn + ni * 16 + l16;
        int rbase = m0 + wm + mi * 16 + quad * 4;
        float bcol = bias[col];
#pragma unroll
        for (int r = 0; r < 4; ++r) {
          int row = rbase + r;
          if (row < M) {
            float v = accs[mi][ni][r] + bcol;
            if (MODE == 0) {
              ((unsigned short*)Cvp)[(size_t)row * N + col] = f2bf(v);
            } else {
              float xi = xres[(size_t)row * 256 + col];
              float o = s * v + (1.f - s) * xi;
              ((float*)Cvp)[(size_t)row * 256 + col] = 0.5f * o + 0.5f * xi;
            }
          }
        }
      }
    }
    __syncthreads();  // Bs consumed; safe to restage next tile
  }
}

// ---------------- CSR build
__global__ __launch_bounds__(256) void hist_kernel(
    const int* __restrict__ ebd, const int* __restrict__ etd, const int* __restrict__ eid,
    int* __restrict__ cnt)
{
  int i = blockIdx.x * 256 + threadIdx.x;
  if (i < cEB)  atomicAdd(&cnt[ebd[i]], 1);
  if (i < cETA) atomicAdd(&cnt[cNI + etd[i]], 1);
  if (i < cEIA) atomicAdd(&cnt[2 * cNI + eid[i]], 1);
}

__global__ __launch_bounds__(256) void scan1_kernel(
    const int* __restrict__ cnt, int* __restrict__ tpre, int* __restrict__ bsum)
{
  __shared__ int wsum[4];
  const int tid = threadIdx.x, lane = tid & 63, wid = tid >> 6;
  const int base = blockIdx.x * 4096 + tid * 16;
  int s = 0;
  if (base + 16 <= cTOT) {
    const int4* p4 = (const int4*)(cnt + base);
    for (int j = 0; j < 4; ++j) { int4 v = p4[j]; s += v.x + v.y + v.z + v.w; }
  } else {
    for (int j = 0; j < 16; ++j) { int i = base + j; if (i < cTOT) s += cnt[i]; }
  }
  int x = s;
  for (int d = 1; d < 64; d <<= 1) { int t = __shfl_up(x, d, 64); if (lane >= d) x += t; }
  if (lane == 63) wsum[wid] = x;
  __syncthreads();
  int wb = 0;
  for (int w = 0; w < 4; ++w) { int v = wsum[w]; if (w < wid) wb += v; }
  tpre[blockIdx.x * 256 + tid] = wb + x - s;
  if (tid == 255) bsum[blockIdx.x] = wb + x;
}

// scan3 with inlined block-base reduction (absorbs old scan2)
__global__ __launch_bounds__(256) void scan3_kernel(
    const int* __restrict__ cnt, const int* __restrict__ tpre,
    const int* __restrict__ bsum, int* __restrict__ off, int* __restrict__ cur)
{
  const int tid = threadIdx.x;
  const int b = blockIdx.x;
  int bb = 0;
  for (int w = 0; w < b; ++w) bb += bsum[w];  // <=36 L2-hot loads
  if (b == 0 && tid == 0) {
    off[cNI] = cEB;
    off[(cNI + 1) + cNI] = cETA;
    off[2 * (cNI + 1) + cNI] = cEIA;
  }
  const int base = b * 4096 + tid * 16;
  int run = bb + tpre[b * 256 + tid];
  for (int j = 0; j < 16; ++j) {
    int i = base + j;
    if (i >= cTOT) break;
    int rel = (i >= 2 * cNI) ? 2 : (i >= cNI ? 1 : 0);
    int pos = i - rel * cNI;
    int relbase = (rel == 0) ? 0 : (rel == 1) ? cEB : (cEB + cETA);
    int val = run - relbase;
    off[rel * (cNI + 1) + pos] = val;
    cur[rel * cNI + pos] = val;
    run += cnt[i];
  }
}

__global__ __launch_bounds__(256) void scatter_kernel(
    const int* __restrict__ ebs, const int* __restrict__ ebd,
    const int* __restrict__ ets, const int* __restrict__ etd,
    const int* __restrict__ eis, const int* __restrict__ eid,
    int* __restrict__ cur,
    int* __restrict__ ss_b, int* __restrict__ ss_t, int* __restrict__ ss_i)
{
  int i = blockIdx.x * 256 + threadIdx.x;
  if (i < cEB)  { int p = atomicAdd(&cur[ebd[i]], 1);           ss_b[p] = ebs[i]; }
  if (i < cETA) { int p = atomicAdd(&cur[cNI + etd[i]], 1);     ss_t[p] = ets[i]; }
  if (i < cEIA) { int p = atomicAdd(&cur[2 * cNI + eid[i]], 1); ss_i[p] = eis[i]; }
}

// ---------------- per-item attention: one wave per item, 4-edge unroll for MLP
__global__ __launch_bounds__(256) void attend_kernel(
    const unsigned short* __restrict__ q,
    const unsigned short* __restrict__ kv_u,
    const unsigned short* __restrict__ kv_t,
    const unsigned short* __restrict__ kv_i,
    const int* __restrict__ off,
    const int* __restrict__ ss_b, const int* __restrict__ ss_t, const int* __restrict__ ss_i,
    unsigned short* __restrict__ gout)
{
  const int wave = threadIdx.x >> 6;
  const int lane = threadIdx.x & 63;
  const int item = blockIdx.x * 4 + wave;
  if (item >= cNI) return;
  ushort4 qu = ((const ushort4*)(q + (size_t)item * 256))[lane];
  const float q0 = bf2f(qu.x), q1 = bf2f(qu.y), q2 = bf2f(qu.z), q3 = bf2f(qu.w);
  float t0 = 0.f, t1 = 0.f, t2 = 0.f, t3 = 0.f;

#define EDGE_DOT(ku, vu, den, a0, a1, a2, a3)                                \
  {                                                                          \
    float p = bf2f(ku.x) * q0 + bf2f(ku.y) * q1 +                            \
              bf2f(ku.z) * q2 + bf2f(ku.w) * q3;                             \
    p += __shfl_xor(p, 1, 8);                                                \
    p += __shfl_xor(p, 2, 8);                                                \
    p += __shfl_xor(p, 4, 8);                                                \
    p = fminf(fmaxf(p, -30.f), 30.f);                                        \
    float ex = __expf(p);                                                    \
    den += ex;                                                               \
    a0 += ex * bf2f(vu.x); a1 += ex * bf2f(vu.y);                            \
    a2 += ex * bf2f(vu.z); a3 += ex * bf2f(vu.w);                            \
  }

#define DO_REL(KV, OFFBASE, SS, NSRC)                                        \
  {                                                                          \
    int e0 = off[(OFFBASE) + item];                                          \
    int e1 = off[(OFFBASE) + item + 1];                                      \
    float den = 0.f, a0 = 0.f, a1 = 0.f, a2 = 0.f, a3 = 0.f;                 \
    int e = e0;                                                              \
    for (; e + 4 <= e1; e += 4) {                                            \
      int s0 = SS[e], s1 = SS[e + 1], s2 = SS[e + 2], s3 = SS[e + 3];        \
      if ((unsigned)s0 >= (unsigned)(NSRC)) s0 = 0;                          \
      if ((unsigned)s1 >= (unsigned)(NSRC)) s1 = 0;                          \
      if ((unsigned)s2 >= (unsigned)(NSRC)) s2 = 0;                          \
      if ((unsigned)s3 >= (unsigned)(NSRC)) s3 = 0;                          \
      const ushort4* p0 = (const ushort4*)((KV) + (size_t)s0 * 512);         \
      const ushort4* p1 = (const ushort4*)((KV) + (size_t)s1 * 512);         \
      const ushort4* p2 = (const ushort4*)((KV) + (size_t)s2 * 512);         \
      const ushort4* p3 = (const ushort4*)((KV) + (size_t)s3 * 512);         \
      ushort4 k0 = p0[lane], v0 = p0[64 + lane];                             \
      ushort4 k1 = p1[lane], v1 = p1[64 + lane];                             \
      ushort4 k2 = p2[lane], v2 = p2[64 + lane];                             \
      ushort4 k3 = p3[lane], v3 = p3[64 + lane];                             \
      EDGE_DOT(k0, v0, den, a0, a1, a2, a3)                                  \
      EDGE_DOT(k1, v1, den, a0, a1, a2, a3)                                  \
      EDGE_DOT(k2, v2, den, a0, a1, a2, a3)                                  \
      EDGE_DOT(k3, v3, den, a0, a1, a2, a3)                                  \
    }                                                                        \
    for (; e + 2 <= e1; e += 2) {                                            \
      int s0 = SS[e], s1 = SS[e + 1];                                        \
      if ((unsigned)s0 >= (unsigned)(NSRC)) s0 = 0;                          \
      if ((unsigned)s1 >= (unsigned)(NSRC)) s1 = 0;                          \
      const ushort4* p0 = (const ushort4*)((KV) + (size_t)s0 * 512);         \
      const ushort4* p1 = (const ushort4*)((KV) + (size_t)s1 * 512);         \
      ushort4 k0 = p0[lane], v0 = p0[64 + lane];                             \
      ushort4 k1 = p1[lane], v1 = p1[64 + lane];                             \
      EDGE_DOT(k0, v0, den, a0, a1, a2, a3)                                  \
      EDGE_DOT(k1, v1, den, a0, a1, a2, a3)                                  \
    }                                                                        \
    if (e < e1) {                                                            \
      int s0 = SS[e];                                                        \
      if ((unsigned)s0 >= (unsigned)(NSRC)) s0 = 0;                          \
      const ushort4* p0 = (const ushort4*)((KV) + (size_t)s0 * 512);         \
      ushort4 k0 = p0[lane], v0 = p0[64 + lane];                             \
      EDGE_DOT(k0, v0, den, a0, a1, a2, a3)                                  \
    }                                                                        \
    float inv = 1.f / (den + 1e-16f);                                        \
    t0 += a0 * inv; t1 += a1 * inv; t2 += a2 * inv; t3 += a3 * inv;          \
  }

  DO_REL(kv_u, 0, ss_b, cNU)
  DO_REL(kv_t, (cNI + 1), ss_t, cNT)
  DO_REL(kv_i, 2 * (cNI + 1), ss_i, cNIM)
#undef DO_REL
#undef EDGE_DOT

  ushort4 o;
  o.x = f2bf(gelu_f(t0));
  o.y = f2bf(gelu_f(t1));
  o.z = f2bf(gelu_f(t2));
  o.w = f2bf(gelu_f(t3));
  ((ushort4*)(gout + (size_t)item * 256))[lane] = o;
}

}  // namespace

extern "C" void kernel_launch(void* const* d_in, const int* in_sizes, int n_in,
                              void* d_out, int out_size, void* d_ws, size_t ws_size,
                              hipStream_t stream) {
  (void)in_sizes; (void)n_in; (void)out_size; (void)ws_size;
  const float* x_user  = (const float*)d_in[0];
  const float* x_item  = (const float*)d_in[1];
  const float* x_taste = (const float*)d_in[2];
  const float* x_image = (const float*)d_in[3];
  const int* eb_src  = (const int*)d_in[4];
  const int* eb_dst  = (const int*)d_in[5];
  const int* eta_src = (const int*)d_in[6];
  const int* eta_dst = (const int*)d_in[7];
  const int* eia_src = (const int*)d_in[8];
  const int* eia_dst = (const int*)d_in[9];
  const float* Wk_u = (const float*)d_in[10];
  const float* bk_u = (const float*)d_in[11];
  const float* Wv_u = (const float*)d_in[12];
  const float* bv_u = (const float*)d_in[13];
  const float* Wk_t = (const float*)d_in[14];
  const float* bk_t = (const float*)d_in[15];
  const float* Wv_t = (const float*)d_in[16];
  const float* bv_t = (const float*)d_in[17];
  const float* Wk_i = (const float*)d_in[18];
  const float* bk_i = (const float*)d_in[19];
  const float* Wv_i = (const float*)d_in[20];
  const float* bv_i = (const float*)d_in[21];
  const float* Wq   = (const float*)d_in[22];
  const float* bq   = (const float*)d_in[23];
  const float* a_b  = (const float*)d_in[24];
  const float* m_b  = (const float*)d_in[25];
  const float* p_b  = (const float*)d_in[26];
  const float* a_t  = (const float*)d_in[27];
  const float* m_t  = (const float*)d_in[28];
  const float* p_t  = (const float*)d_in[29];
  const float* a_i  = (const float*)d_in[30];
  const float* m_i  = (const float*)d_in[31];
  const float* p_i  = (const float*)d_in[32];
  const float* Wo   = (const float*)d_in[33];
  const float* bo   = (const float*)d_in[34];
  const float* skip = (const float*)d_in[35];

  char* p = (char*)d_ws;
  auto alloc = [&](size_t n) -> char* {
    char* r = p;
    p += (n + 255) & ~(size_t)255;
    return r;
  };
  unsigned short* q      = (unsigned short*)alloc((size_t)cNI * 256 * 2);
  unsigned short* kv_u   = (unsigned short*)alloc((size_t)cNU * 512 * 2);
  unsigned short* kv_t   = (unsigned short*)alloc((size_t)cNT * 512 * 2);
  unsigned short* kv_i   = (unsigned short*)alloc((size_t)cNIM * 512 * 2);
  unsigned short* gagg   = (unsigned short*)alloc((size_t)cNI * 256 * 2);
  unsigned short* WkvT_u = (unsigned short*)alloc(512 * 256 * 2);
  unsigned short* WkvT_t = (unsigned short*)alloc(512 * 256 * 2);
  unsigned short* WkvT_i = (unsigned short*)alloc(512 * 256 * 2);
  unsigned short* WqT    = (unsigned short*)alloc(256 * 256 * 2);
  unsigned short* WoT    = (unsigned short*)alloc(256 * 256 * 2);
  float* bkv_u = (float*)alloc(512 * 4);
  float* bkv_t = (float*)alloc(512 * 4);
  float* bkv_i = (float*)alloc(512 * 4);
  float* bqf   = (float*)alloc(256 * 4);
  float* bof   = (float*)alloc(256 * 4);
  int* cnt   = (int*)alloc((size_t)cTOT * 4);
  int* off   = (int*)alloc((size_t)3 * (cNI + 1) * 4);
  int* cur   = (int*)alloc((size_t)cTOT * 4);
  int* tpre  = (int*)alloc((size_t)cSCANB * 256 * 4);
  int* bsum  = (int*)alloc(64 * 4);
  int* ss_b = (int*)alloc((size_t)cEB * 4);
  int* ss_t = (int*)alloc((size_t)cETA * 4);
  int* ss_i = (int*)alloc((size_t)cEIA * 4);

  hipMemsetAsync(cnt, 0, (size_t)cTOT * 4, stream);

  combine_kernel<<<2048, 256, 0, stream>>>(
      Wk_u, bk_u, Wv_u, bv_u, Wk_t, bk_t, Wv_t, bv_t, Wk_i, bk_i, Wv_i, bv_i,
      a_b, m_b, p_b, a_t, m_t, p_t, a_i, m_i, p_i,
      Wq, bq, Wo, bo,
      WkvT_u, bkv_u, WkvT_t, bkv_t, WkvT_i, bkv_i, WqT, bqf, WoT, bof);

  // fused projection GEMMs: q | kv_u | kv_t | kv_i  (2659 strips)
  gemm_strip_kernel<0><<<cSQ + cSU + cST + cSIM, 256, 0, stream>>>(
      x_item,  WqT,    bqf,   q,    cNI,  256,
      x_user,  WkvT_u, bkv_u, kv_u, cNU,  512,
      x_taste, WkvT_t, bkv_t, kv_t, cNT,  512,
      x_image, WkvT_i, bkv_i, kv_i, cNIM, 512,
      nullptr, nullptr);

  hist_kernel<<<1563, 256, 0, stream>>>(eb_dst, eta_dst, eia_dst, cnt);
  scan1_kernel<<<cSCANB, 256, 0, stream>>>(cnt, tpre, bsum);
  scan3_kernel<<<cSCANB, 256, 0, stream>>>(cnt, tpre, bsum, off, cur);
  scatter_kernel<<<1563, 256, 0, stream>>>(eb_src, eb_dst, eta_src, eta_dst, eia_src, eia_dst,
                                           cur, ss_b, ss_t, ss_i);

  attend_kernel<<<12500, 256, 0, stream>>>(q, kv_u, kv_t, kv_i, off, ss_b, ss_t, ss_i, gagg);

  // final GEMM + gelu'd input is gagg; epilogue does skip-blend + residual
  gemm_strip_kernel<1><<<cSQ, 256, 0, stream>>>(
      gagg, WoT, bof, d_out, cNI, 256,
      nullptr, nullptr, nullptr, nullptr, 0, 0,
      nullptr, nullptr, nullptr, nullptr, 0, 0,
      nullptr, nullptr, nullptr, nullptr, 0, 0,
      x_item, skip);
}